// Round 8
// baseline (585.736 us; speedup 1.0000x reference)
//
#include <hip/hip_runtime.h>
#include <hip/hip_bf16.h>

typedef char  i8x4  __attribute__((ext_vector_type(4)));
typedef char  i8x8  __attribute__((ext_vector_type(8)));
typedef char  i8x16 __attribute__((ext_vector_type(16)));
typedef float f32x4 __attribute__((ext_vector_type(4)));
typedef int   i32x4 __attribute__((ext_vector_type(4)));
typedef __bf16 bf16x8 __attribute__((ext_vector_type(8)));

#define M_DIM 2048
#define K_DIM 2048
#define V_DIM 50257
#define V_PAD 50304                 // 393 * 128 = 786 * 64
#define BM 128
#define BN 128
#define BK8 128                     // i8 K-tile (128 B per LDS row)
#define NT8 (K_DIM / BK8)           // 16
#define CVTW_BX 786
#define CVTW_BLOCKS (CVTW_BX * 32)  // 64x64 tiles over [K_DIM][V_PAD]

__device__ __forceinline__ void gl_lds16(const void* g, void* l) {
    __builtin_amdgcn_global_load_lds(
        (const __attribute__((address_space(1))) void*)g,
        (__attribute__((address_space(3))) void*)l, 16, 0, 0);
}

// ---------- merged prepass: W[k][v] i32 -> Wt8[v][k] i8 (+pad), and A f32 -> i8 ----------
// Blocks [0, CVTW_BLOCKS): one 64x64 W transpose tile each (nt loads of wq).
// Blocks [CVTW_BLOCKS, +M_DIM): one A row each: amax reduce + quantize.
__global__ __launch_bounds__(256)
void prep(const float* __restrict__ hs, const int* __restrict__ wq,
          char* __restrict__ a8, float* __restrict__ rowsc,
          char* __restrict__ wt8)
{
    __shared__ __attribute__((aligned(16))) char shm[64 * 80];
    const int bid = blockIdx.x;
    const int t   = threadIdx.x;

    if (bid < CVTW_BLOCKS) {
        // ---- cvtW tile ----
        char (*tls)[80] = (char (*)[80])shm;
        const int v0 = (bid % CVTW_BX) * 64;
        const int k0 = (bid / CVTW_BX) * 64;
        const int vb = t & 15, kb = t >> 4;
        const bool edge = (v0 + 64 > V_DIM);

        char cv[4][4];                     // [j=k][i=v]
#pragma unroll
        for (int j = 0; j < 4; ++j) {
            const int* p = wq + (size_t)(k0 + kb * 4 + j) * V_DIM + v0 + vb * 4;
            if (!edge) {
                i32x4 w = __builtin_nontemporal_load((const i32x4*)p);
#pragma unroll
                for (int i = 0; i < 4; ++i) cv[j][i] = (char)w[i];
            } else {
#pragma unroll
                for (int i = 0; i < 4; ++i) {
                    int v = v0 + vb * 4 + i;
                    cv[j][i] = (v < V_DIM) ? (char)p[i] : (char)0;
                }
            }
        }
#pragma unroll
        for (int i = 0; i < 4; ++i) {
            i8x4 c = { cv[0][i], cv[1][i], cv[2][i], cv[3][i] };
            *(i8x4*)(&tls[vb * 4 + i][kb * 4]) = c;
        }
        __syncthreads();
        const int v = t >> 2, ko = (t & 3) * 16;
        i8x16 r = *(const i8x16*)(&tls[v][ko]);
        *(i8x16*)(wt8 + (size_t)(v0 + v) * K_DIM + k0 + ko) = r;   // keep in L2/L3
    } else {
        // ---- cvtA row ----
        float* red = (float*)shm;
        const int row = bid - CVTW_BLOCKS;
        const float* rp = hs + (size_t)row * K_DIM + t * 8;
        f32x4 v0 = __builtin_nontemporal_load((const f32x4*)rp);
        f32x4 v1 = __builtin_nontemporal_load((const f32x4*)(rp + 4));
        float amax = 0.0f;
#pragma unroll
        for (int j = 0; j < 4; ++j)
            amax = fmaxf(amax, fmaxf(fabsf(v0[j]), fabsf(v1[j])));
#pragma unroll
        for (int off = 32; off; off >>= 1)
            amax = fmaxf(amax, __shfl_xor(amax, off, 64));
        if ((t & 63) == 0) red[t >> 6] = amax;
        __syncthreads();
        amax = fmaxf(fmaxf(red[0], red[1]), fmaxf(red[2], red[3]));
        amax = fmaxf(amax, 1e-30f);
        const float s = 127.0f / amax;
        i8x8 o;
#pragma unroll
        for (int j = 0; j < 4; ++j) {
            o[j]     = (char)__float2int_rn(v0[j] * s);
            o[4 + j] = (char)__float2int_rn(v1[j] * s);
        }
        *(i8x8*)(a8 + (size_t)row * K_DIM + t * 8) = o;
        if (t == 0) rowsc[row] = amax / 127.0f;
    }
}

// ---------- main GEMM: int8 MFMA, m97 structure + T2 swizzle + 4 blocks/CU ----------
// 128x128 tile, BK=128 i8 (NT=16), single LDS buffer (32 KB), 2 barriers/K-step.
// LDS[row][cb] = logical[row][cb ^ ((row&7)*16)] via pre-swizzled gload source;
// ds_read applies the same XOR -> conflict-free. acc is EXACT i32.
// Epilogue: out = f32(acc) * (rowsc[m]*scale[n]) + bias[n], NON-TEMPORAL stores
// (don't evict Wt8/A8 from L3 with the 412 MB output stream).
__global__ __launch_bounds__(256, 4)
void lmhead_gemm_i8(const char* __restrict__ A8, const float* __restrict__ rowsc,
                    const char* __restrict__ Bt8,
                    const float* __restrict__ scale, const float* __restrict__ bias,
                    float* __restrict__ out)
{
    __shared__ __attribute__((aligned(16))) char As[BM * BK8];   // 16 KB
    __shared__ __attribute__((aligned(16))) char Bs[BN * BK8];   // 16 KB

    const int tid  = threadIdx.x;
    const int lane = tid & 63;
    const int wv   = tid >> 6;
    const int wm   = wv >> 1, wn = wv & 1;

    // bijective XCD-chunked swizzle: 6288 blocks, 6288/8 = 786 exact.
    int bid  = blockIdx.x;
    int wgid = (bid & 7) * 786 + (bid >> 3);
    const int m0 = (wgid & 15) * BM;          // M fast-varying within an XCD chunk
    const int n0 = (wgid >> 4) * BN;

    const int hi = lane >> 4, la = lane & 15;
    // swizzled ds_read byte offsets for kk=0/1 (frag = 16 i8 at k = kk*64 + hi*16)
    const int colo0 = (0 * 64 + hi * 16) ^ ((la & 7) << 4);
    const int colo1 = (1 * 64 + hi * 16) ^ ((la & 7) << 4);

    i32x4 acc[4][4];
#pragma unroll
    for (int i = 0; i < 4; ++i)
#pragma unroll
        for (int j = 0; j < 4; ++j) acc[i][j] = (i32x4)(0);

    // staging: lane = (l8 = row-in-granule, l7 = chunk); pre-swizzled source chunk
    const int l8 = lane >> 3, l7 = lane & 7;
    const int csrc = (l7 ^ l8) * 16;          // bytes within the 128-B row

#pragma unroll 1
    for (int kt = 0; kt < NT8; ++kt) {
        // ---- stage: 16 KB each of A,B via 4+4 gload_lds(1KB) per wave ----
#pragma unroll
        for (int i = 0; i < 4; ++i) {
            int seg = wv * 4 + i;                                // 0..15, wave-uniform
            int row = seg * 8 + l8;
            gl_lds16(A8  + (size_t)(m0 + row) * K_DIM + kt * BK8 + csrc, As + seg * 1024);
            gl_lds16(Bt8 + (size_t)(n0 + row) * K_DIM + kt * BK8 + csrc, Bs + seg * 1024);
        }
        __syncthreads();   // drains vmcnt(0): tiles resident

        // ---- compute: 16 ds_read_b128 (conflict-free) + 32 MFMA(16x16x64 i8) ----
#pragma unroll
        for (int kk = 0; kk < 2; ++kk) {
            const int colo = kk ? colo1 : colo0;
            i32x4 af[4], bf[4];
#pragma unroll
            for (int f = 0; f < 4; ++f)
                af[f] = *(const i32x4*)(As + (wm * 64 + f * 16 + la) * BK8 + colo);
#pragma unroll
            for (int f = 0; f < 4; ++f)
                bf[f] = *(const i32x4*)(Bs + (wn * 64 + f * 16 + la) * BK8 + colo);
#pragma unroll
            for (int fm = 0; fm < 4; ++fm)
#pragma unroll
                for (int fn = 0; fn < 4; ++fn)
                    acc[fm][fn] = __builtin_amdgcn_mfma_i32_16x16x64_i8(
                        af[fm], bf[fn], acc[fm][fn], 0, 0, 0);
        }
        __syncthreads();   // compute done before next overwrite
    }

    // ---- epilogue: fn INNER (4x64B segments merge); non-temporal stores ----
    float sc[4], bi[4];
    bool  okn[4];
#pragma unroll
    for (int fn = 0; fn < 4; ++fn) {
        int n = n0 + wn * 64 + fn * 16 + la;
        okn[fn] = (n < V_DIM);
        int nc = okn[fn] ? n : 0;
        sc[fn] = scale[nc];
        bi[fn] = bias[nc];
    }
#pragma unroll
    for (int f = 0; f < 4; ++f) {
#pragma unroll
        for (int r = 0; r < 4; ++r) {
            int m = m0 + wm * 64 + f * 16 + hi * 4 + r;
            float sa = rowsc[m];
            float* op = out + (size_t)m * V_DIM + n0 + wn * 64 + la;
#pragma unroll
            for (int fn = 0; fn < 4; ++fn)
                if (okn[fn])
                    __builtin_nontemporal_store(
                        (float)acc[f][fn][r] * (sa * sc[fn]) + bi[fn], &op[fn * 16]);
        }
    }
}

// ================= fallback (R0 kernel, used only if ws too small) =================
__global__ __launch_bounds__(256, 2)
void lmhead_gemm_fb(const float* __restrict__ hs, const int* __restrict__ wq,
                    const float* __restrict__ scale, const float* __restrict__ bias,
                    float* __restrict__ out)
{
    __shared__ __attribute__((aligned(16))) __bf16 smem[2 * 2 * 128 * 64];
    const int tid  = threadIdx.x;
    const int lane = tid & 63;
    const int wv   = tid >> 6;
    const int wm   = wv >> 1, wn = wv & 1;
    const int m0   = blockIdx.x * 128;
    const int n0   = blockIdx.y * 128;
    const bool edge = (n0 + 128 > V_DIM);
    const int ngB = tid >> 3, kgB = tid & 7;

    float a_reg[4][8];
    int   b_reg[8][4];
    f32x4 acc[4][4];
#pragma unroll
    for (int i = 0; i < 4; ++i)
#pragma unroll
        for (int j = 0; j < 4; ++j) acc[i][j] = (f32x4)(0.0f);

    auto load_tile = [&](int kt) {
#pragma unroll
        for (int g = 0; g < 4; ++g) {
            int c = tid + 256 * g;
            int row = c >> 3, kg = c & 7;
            const float* p = hs + (size_t)(m0 + row) * K_DIM + (size_t)kt * 64 + kg * 8;
            f32x4 v0 = *(const f32x4*)p;
            f32x4 v1 = *(const f32x4*)(p + 4);
#pragma unroll
            for (int j = 0; j < 4; ++j) { a_reg[g][j] = v0[j]; a_reg[g][4 + j] = v1[j]; }
        }
        const int kbase = kt * 64 + kgB * 8;
        if (!edge) {
            const int* p = wq + (size_t)kbase * V_DIM + n0 + ngB * 4;
#pragma unroll
            for (int j = 0; j < 8; ++j) {
                i32x4 v = *(const i32x4*)(p + (size_t)j * V_DIM);
#pragma unroll
                for (int i = 0; i < 4; ++i) b_reg[j][i] = v[i];
            }
        } else {
#pragma unroll
            for (int j = 0; j < 8; ++j)
#pragma unroll
                for (int i = 0; i < 4; ++i) {
                    int n = n0 + ngB * 4 + i;
                    b_reg[j][i] = (n < V_DIM) ? wq[(size_t)(kbase + j) * V_DIM + n] : 0;
                }
        }
    };
    auto store_tile = [&](int buf) {
        __bf16* As = smem + buf * (2 * 128 * 64);
        __bf16* Bs = As + 128 * 64;
#pragma unroll
        for (int g = 0; g < 4; ++g) {
            int c = tid + 256 * g;
            int row = c >> 3, kg = c & 7;
            bf16x8 t;
#pragma unroll
            for (int j = 0; j < 8; ++j) t[j] = (__bf16)a_reg[g][j];
            *(bf16x8*)(As + row * 64 + ((kg * 8) ^ ((row & 7) << 3))) = t;
        }
#pragma unroll
        for (int i = 0; i < 4; ++i) {
            int row = ngB * 4 + i;
            bf16x8 t;
#pragma unroll
            for (int j = 0; j < 8; ++j) t[j] = (__bf16)(float)b_reg[j][i];
            *(bf16x8*)(Bs + row * 64 + ((kgB * 8) ^ ((row & 7) << 3))) = t;
        }
    };
    auto compute = [&](int buf) {
        const __bf16* As = smem + buf * (2 * 128 * 64);
        const __bf16* Bs = As + 128 * 64;
        const int hi = lane >> 4, la = lane & 15;
#pragma unroll
        for (int kk = 0; kk < 2; ++kk) {
            bf16x8 af[4], bfr[4];
#pragma unroll
            for (int f = 0; f < 4; ++f) {
                int row = wm * 64 + f * 16 + la;
                af[f] = *(const bf16x8*)(As + row * 64 + ((kk * 32 + hi * 8) ^ ((row & 7) << 3)));
            }
#pragma unroll
            for (int f = 0; f < 4; ++f) {
                int row = wn * 64 + f * 16 + la;
                bfr[f] = *(const bf16x8*)(Bs + row * 64 + ((kk * 32 + hi * 8) ^ ((row & 7) << 3)));
            }
#pragma unroll
            for (int fm = 0; fm < 4; ++fm)
#pragma unroll
                for (int fn = 0; fn < 4; ++fn)
                    acc[fm][fn] = __builtin_amdgcn_mfma_f32_16x16x32_bf16(
                        af[fm], bfr[fn], acc[fm][fn], 0, 0, 0);
        }
    };

    load_tile(0); store_tile(0); __syncthreads();
    int cur = 0;
#pragma unroll 1
    for (int kt = 0; kt < (K_DIM / 64) - 1; ++kt) {
        load_tile(kt + 1);
        compute(cur);
        store_tile(cur ^ 1);
        __syncthreads();
        cur ^= 1;
    }
    compute(cur);

    const int hi = lane >> 4, la = lane & 15;
#pragma unroll
    for (int fn = 0; fn < 4; ++fn) {
        int n = n0 + wn * 64 + fn * 16 + la;
        bool ok = (n < V_DIM);
        int nc = ok ? n : 0;
        float sc = scale[nc];
        float bi = bias[nc];
#pragma unroll
        for (int fm = 0; fm < 4; ++fm) {
            int m = m0 + wm * 64 + fm * 16 + hi * 4;
            float* op = out + (size_t)m * V_DIM + n;
#pragma unroll
            for (int r = 0; r < 4; ++r)
                if (ok) op[(size_t)r * V_DIM] = acc[fm][fn][r] * sc + bi;
        }
    }
}

extern "C" void kernel_launch(void* const* d_in, const int* in_sizes, int n_in,
                              void* d_out, int out_size, void* d_ws, size_t ws_size,
                              hipStream_t stream) {
    const float* hs    = (const float*)d_in[0];
    const int*   wq    = (const int*)d_in[1];
    const float* scale = (const float*)d_in[2];
    const float* bias  = (const float*)d_in[3];
    float*       out   = (float*)d_out;

    // ws layout: a8 [0, 4MB) | rowsc [4MB, +8KB) | Wt8 [8MB, +103MB)
    const size_t offRS = (size_t)M_DIM * K_DIM;            // 4 MB
    const size_t offW  = offRS + (4u << 20);               // 8 MB
    const size_t need  = offW + (size_t)V_PAD * K_DIM;     // ~111 MB
    if (ws_size >= need) {
        char*  a8    = (char*)d_ws;
        float* rowsc = (float*)((char*)d_ws + offRS);
        char*  wt8   = (char*)d_ws + offW;
        prep<<<dim3(CVTW_BLOCKS + M_DIM), dim3(256), 0, stream>>>(hs, wq, a8, rowsc, wt8);
        lmhead_gemm_i8<<<dim3(16 * (V_PAD / BN)), dim3(256), 0, stream>>>(
            a8, rowsc, wt8, scale, bias, out);
    } else {
        lmhead_gemm_fb<<<dim3(M_DIM / 128, (V_DIM + 127) / 128), dim3(256), 0, stream>>>(
            hs, wq, scale, bias, out);
    }
}

// Round 9
// 479.573 us; speedup vs baseline: 1.2214x; 1.2214x over previous
//
#include <hip/hip_runtime.h>
#include <hip/hip_bf16.h>

typedef char  i8x4  __attribute__((ext_vector_type(4)));
typedef char  i8x8  __attribute__((ext_vector_type(8)));
typedef char  i8x16 __attribute__((ext_vector_type(16)));
typedef float f32x4 __attribute__((ext_vector_type(4)));
typedef int   i32x4 __attribute__((ext_vector_type(4)));
typedef __bf16 bf16x8 __attribute__((ext_vector_type(8)));

#define M_DIM 2048
#define K_DIM 2048
#define V_DIM 50257
#define V_PAD 50304                 // 393 * 128 = 786 * 64
#define BM 128
#define BN 128
#define BK8 128                     // i8 K-tile (128 B per LDS row)
#define NT8 (K_DIM / BK8)           // 16
#define CVTW_BX 786
#define CVTW_BLOCKS (CVTW_BX * 32)  // 64x64 tiles over [K_DIM][V_PAD]

__device__ __forceinline__ void gl_lds16(const void* g, void* l) {
    __builtin_amdgcn_global_load_lds(
        (const __attribute__((address_space(1))) void*)g,
        (__attribute__((address_space(3))) void*)l, 16, 0, 0);
}

// ---------- merged prepass: W[k][v] i32 -> Wt8[v][k] i8 (+pad), and A f32 -> i8 ----------
// Blocks [0, CVTW_BLOCKS): one 64x64 W transpose tile each (nt loads of wq).
// Blocks [CVTW_BLOCKS, +M_DIM): one A row each: amax reduce + quantize.
__global__ __launch_bounds__(256)
void prep(const float* __restrict__ hs, const int* __restrict__ wq,
          char* __restrict__ a8, float* __restrict__ rowsc,
          char* __restrict__ wt8)
{
    __shared__ __attribute__((aligned(16))) char shm[64 * 80];
    const int bid = blockIdx.x;
    const int t   = threadIdx.x;

    if (bid < CVTW_BLOCKS) {
        // ---- cvtW tile ----
        char (*tls)[80] = (char (*)[80])shm;
        const int v0 = (bid % CVTW_BX) * 64;
        const int k0 = (bid / CVTW_BX) * 64;
        const int vb = t & 15, kb = t >> 4;
        const bool edge = (v0 + 64 > V_DIM);

        char cv[4][4];                     // [j=k][i=v]
#pragma unroll
        for (int j = 0; j < 4; ++j) {
            const int* p = wq + (size_t)(k0 + kb * 4 + j) * V_DIM + v0 + vb * 4;
            if (!edge) {
                i32x4 w = __builtin_nontemporal_load((const i32x4*)p);
#pragma unroll
                for (int i = 0; i < 4; ++i) cv[j][i] = (char)w[i];
            } else {
#pragma unroll
                for (int i = 0; i < 4; ++i) {
                    int v = v0 + vb * 4 + i;
                    cv[j][i] = (v < V_DIM) ? (char)p[i] : (char)0;
                }
            }
        }
#pragma unroll
        for (int i = 0; i < 4; ++i) {
            i8x4 c = { cv[0][i], cv[1][i], cv[2][i], cv[3][i] };
            *(i8x4*)(&tls[vb * 4 + i][kb * 4]) = c;
        }
        __syncthreads();
        const int v = t >> 2, ko = (t & 3) * 16;
        i8x16 r = *(const i8x16*)(&tls[v][ko]);
        *(i8x16*)(wt8 + (size_t)(v0 + v) * K_DIM + k0 + ko) = r;   // regular store: stays in L2/L3
    } else {
        // ---- cvtA row ----
        float* red = (float*)shm;
        const int row = bid - CVTW_BLOCKS;
        const float* rp = hs + (size_t)row * K_DIM + t * 8;
        f32x4 v0 = __builtin_nontemporal_load((const f32x4*)rp);
        f32x4 v1 = __builtin_nontemporal_load((const f32x4*)(rp + 4));
        float amax = 0.0f;
#pragma unroll
        for (int j = 0; j < 4; ++j)
            amax = fmaxf(amax, fmaxf(fabsf(v0[j]), fabsf(v1[j])));
#pragma unroll
        for (int off = 32; off; off >>= 1)
            amax = fmaxf(amax, __shfl_xor(amax, off, 64));
        if ((t & 63) == 0) red[t >> 6] = amax;
        __syncthreads();
        amax = fmaxf(fmaxf(red[0], red[1]), fmaxf(red[2], red[3]));
        amax = fmaxf(amax, 1e-30f);
        const float s = 127.0f / amax;
        i8x8 o;
#pragma unroll
        for (int j = 0; j < 4; ++j) {
            o[j]     = (char)__float2int_rn(v0[j] * s);
            o[4 + j] = (char)__float2int_rn(v1[j] * s);
        }
        *(i8x8*)(a8 + (size_t)row * K_DIM + t * 8) = o;
        if (t == 0) rowsc[row] = amax / 127.0f;
    }
}

// ---------- main GEMM: int8 MFMA, m97 structure + T2 swizzle + 4 blocks/CU ----------
// 128x128 tile, BK=128 i8 (NT=16), single LDS buffer (32 KB), 2 barriers/K-step.
// LDS[row][cb] = logical[row][cb ^ ((row&7)*16)] via pre-swizzled gload source;
// ds_read applies the same XOR -> conflict-free. acc is EXACT i32.
// Epilogue: REGULAR stores (R7 lesson: nt stores break L2 write-merging,
// WRITE_SIZE 428->780 MB); fn-inner order so 4x64B segments merge per row.
__global__ __launch_bounds__(256, 4)
void lmhead_gemm_i8(const char* __restrict__ A8, const float* __restrict__ rowsc,
                    const char* __restrict__ Bt8,
                    const float* __restrict__ scale, const float* __restrict__ bias,
                    float* __restrict__ out)
{
    __shared__ __attribute__((aligned(16))) char As[BM * BK8];   // 16 KB
    __shared__ __attribute__((aligned(16))) char Bs[BN * BK8];   // 16 KB

    const int tid  = threadIdx.x;
    const int lane = tid & 63;
    const int wv   = tid >> 6;
    const int wm   = wv >> 1, wn = wv & 1;

    // bijective XCD-chunked swizzle: 6288 blocks, 6288/8 = 786 exact.
    int bid  = blockIdx.x;
    int wgid = (bid & 7) * 786 + (bid >> 3);
    const int m0 = (wgid & 15) * BM;          // M fast-varying within an XCD chunk
    const int n0 = (wgid >> 4) * BN;

    const int hi = lane >> 4, la = lane & 15;
    // swizzled ds_read byte offsets for kk=0/1 (frag = 16 i8 at k = kk*64 + hi*16)
    const int colo0 = (0 * 64 + hi * 16) ^ ((la & 7) << 4);
    const int colo1 = (1 * 64 + hi * 16) ^ ((la & 7) << 4);

    i32x4 acc[4][4];
#pragma unroll
    for (int i = 0; i < 4; ++i)
#pragma unroll
        for (int j = 0; j < 4; ++j) acc[i][j] = (i32x4)(0);

    // staging: lane = (l8 = row-in-granule, l7 = chunk); pre-swizzled source chunk
    const int l8 = lane >> 3, l7 = lane & 7;
    const int csrc = (l7 ^ l8) * 16;          // bytes within the 128-B row

#pragma unroll 1
    for (int kt = 0; kt < NT8; ++kt) {
        // ---- stage: 16 KB each of A,B via 4+4 gload_lds(1KB) per wave ----
#pragma unroll
        for (int i = 0; i < 4; ++i) {
            int seg = wv * 4 + i;                                // 0..15, wave-uniform
            int row = seg * 8 + l8;
            gl_lds16(A8  + (size_t)(m0 + row) * K_DIM + kt * BK8 + csrc, As + seg * 1024);
            gl_lds16(Bt8 + (size_t)(n0 + row) * K_DIM + kt * BK8 + csrc, Bs + seg * 1024);
        }
        __syncthreads();   // drains vmcnt(0): tiles resident

        // ---- compute: 16 ds_read_b128 (conflict-free) + 32 MFMA(16x16x64 i8) ----
#pragma unroll
        for (int kk = 0; kk < 2; ++kk) {
            const int colo = kk ? colo1 : colo0;
            i32x4 af[4], bf[4];
#pragma unroll
            for (int f = 0; f < 4; ++f)
                af[f] = *(const i32x4*)(As + (wm * 64 + f * 16 + la) * BK8 + colo);
#pragma unroll
            for (int f = 0; f < 4; ++f)
                bf[f] = *(const i32x4*)(Bs + (wn * 64 + f * 16 + la) * BK8 + colo);
#pragma unroll
            for (int fm = 0; fm < 4; ++fm)
#pragma unroll
                for (int fn = 0; fn < 4; ++fn)
                    acc[fm][fn] = __builtin_amdgcn_mfma_i32_16x16x64_i8(
                        af[fm], bf[fn], acc[fm][fn], 0, 0, 0);
        }
        __syncthreads();   // compute done before next overwrite
    }

    // ---- epilogue: fn INNER (4x64B segments of each row merge in L2) ----
    float sc[4], bi[4];
    bool  okn[4];
#pragma unroll
    for (int fn = 0; fn < 4; ++fn) {
        int n = n0 + wn * 64 + fn * 16 + la;
        okn[fn] = (n < V_DIM);
        int nc = okn[fn] ? n : 0;
        sc[fn] = scale[nc];
        bi[fn] = bias[nc];
    }
#pragma unroll
    for (int f = 0; f < 4; ++f) {
#pragma unroll
        for (int r = 0; r < 4; ++r) {
            int m = m0 + wm * 64 + f * 16 + hi * 4 + r;
            float sa = rowsc[m];
            float* op = out + (size_t)m * V_DIM + n0 + wn * 64 + la;
#pragma unroll
            for (int fn = 0; fn < 4; ++fn)
                if (okn[fn]) op[fn * 16] = (float)acc[f][fn][r] * (sa * sc[fn]) + bi[fn];
        }
    }
}

// ================= fallback (R0 kernel, used only if ws too small) =================
__global__ __launch_bounds__(256, 2)
void lmhead_gemm_fb(const float* __restrict__ hs, const int* __restrict__ wq,
                    const float* __restrict__ scale, const float* __restrict__ bias,
                    float* __restrict__ out)
{
    __shared__ __attribute__((aligned(16))) __bf16 smem[2 * 2 * 128 * 64];
    const int tid  = threadIdx.x;
    const int lane = tid & 63;
    const int wv   = tid >> 6;
    const int wm   = wv >> 1, wn = wv & 1;
    const int m0   = blockIdx.x * 128;
    const int n0   = blockIdx.y * 128;
    const bool edge = (n0 + 128 > V_DIM);
    const int ngB = tid >> 3, kgB = tid & 7;

    float a_reg[4][8];
    int   b_reg[8][4];
    f32x4 acc[4][4];
#pragma unroll
    for (int i = 0; i < 4; ++i)
#pragma unroll
        for (int j = 0; j < 4; ++j) acc[i][j] = (f32x4)(0.0f);

    auto load_tile = [&](int kt) {
#pragma unroll
        for (int g = 0; g < 4; ++g) {
            int c = tid + 256 * g;
            int row = c >> 3, kg = c & 7;
            const float* p = hs + (size_t)(m0 + row) * K_DIM + (size_t)kt * 64 + kg * 8;
            f32x4 v0 = *(const f32x4*)p;
            f32x4 v1 = *(const f32x4*)(p + 4);
#pragma unroll
            for (int j = 0; j < 4; ++j) { a_reg[g][j] = v0[j]; a_reg[g][4 + j] = v1[j]; }
        }
        const int kbase = kt * 64 + kgB * 8;
        if (!edge) {
            const int* p = wq + (size_t)kbase * V_DIM + n0 + ngB * 4;
#pragma unroll
            for (int j = 0; j < 8; ++j) {
                i32x4 v = *(const i32x4*)(p + (size_t)j * V_DIM);
#pragma unroll
                for (int i = 0; i < 4; ++i) b_reg[j][i] = v[i];
            }
        } else {
#pragma unroll
            for (int j = 0; j < 8; ++j)
#pragma unroll
                for (int i = 0; i < 4; ++i) {
                    int n = n0 + ngB * 4 + i;
                    b_reg[j][i] = (n < V_DIM) ? wq[(size_t)(kbase + j) * V_DIM + n] : 0;
                }
        }
    };
    auto store_tile = [&](int buf) {
        __bf16* As = smem + buf * (2 * 128 * 64);
        __bf16* Bs = As + 128 * 64;
#pragma unroll
        for (int g = 0; g < 4; ++g) {
            int c = tid + 256 * g;
            int row = c >> 3, kg = c & 7;
            bf16x8 t;
#pragma unroll
            for (int j = 0; j < 8; ++j) t[j] = (__bf16)a_reg[g][j];
            *(bf16x8*)(As + row * 64 + ((kg * 8) ^ ((row & 7) << 3))) = t;
        }
#pragma unroll
        for (int i = 0; i < 4; ++i) {
            int row = ngB * 4 + i;
            bf16x8 t;
#pragma unroll
            for (int j = 0; j < 8; ++j) t[j] = (__bf16)(float)b_reg[j][i];
            *(bf16x8*)(Bs + row * 64 + ((kgB * 8) ^ ((row & 7) << 3))) = t;
        }
    };
    auto compute = [&](int buf) {
        const __bf16* As = smem + buf * (2 * 128 * 64);
        const __bf16* Bs = As + 128 * 64;
        const int hi = lane >> 4, la = lane & 15;
#pragma unroll
        for (int kk = 0; kk < 2; ++kk) {
            bf16x8 af[4], bfr[4];
#pragma unroll
            for (int f = 0; f < 4; ++f) {
                int row = wm * 64 + f * 16 + la;
                af[f] = *(const bf16x8*)(As + row * 64 + ((kk * 32 + hi * 8) ^ ((row & 7) << 3)));
            }
#pragma unroll
            for (int f = 0; f < 4; ++f) {
                int row = wn * 64 + f * 16 + la;
                bfr[f] = *(const bf16x8*)(Bs + row * 64 + ((kk * 32 + hi * 8) ^ ((row & 7) << 3)));
            }
#pragma unroll
            for (int fm = 0; fm < 4; ++fm)
#pragma unroll
                for (int fn = 0; fn < 4; ++fn)
                    acc[fm][fn] = __builtin_amdgcn_mfma_f32_16x16x32_bf16(
                        af[fm], bfr[fn], acc[fm][fn], 0, 0, 0);
        }
    };

    load_tile(0); store_tile(0); __syncthreads();
    int cur = 0;
#pragma unroll 1
    for (int kt = 0; kt < (K_DIM / 64) - 1; ++kt) {
        load_tile(kt + 1);
        compute(cur);
        store_tile(cur ^ 1);
        __syncthreads();
        cur ^= 1;
    }
    compute(cur);

    const int hi = lane >> 4, la = lane & 15;
#pragma unroll
    for (int fn = 0; fn < 4; ++fn) {
        int n = n0 + wn * 64 + fn * 16 + la;
        bool ok = (n < V_DIM);
        int nc = ok ? n : 0;
        float sc = scale[nc];
        float bi = bias[nc];
#pragma unroll
        for (int fm = 0; fm < 4; ++fm) {
            int m = m0 + wm * 64 + fm * 16 + hi * 4;
            float* op = out + (size_t)m * V_DIM + n;
#pragma unroll
            for (int r = 0; r < 4; ++r)
                if (ok) op[(size_t)r * V_DIM] = acc[fm][fn][r] * sc + bi;
        }
    }
}

extern "C" void kernel_launch(void* const* d_in, const int* in_sizes, int n_in,
                              void* d_out, int out_size, void* d_ws, size_t ws_size,
                              hipStream_t stream) {
    const float* hs    = (const float*)d_in[0];
    const int*   wq    = (const int*)d_in[1];
    const float* scale = (const float*)d_in[2];
    const float* bias  = (const float*)d_in[3];
    float*       out   = (float*)d_out;

    // ws layout: a8 [0, 4MB) | rowsc [4MB, +8KB) | Wt8 [8MB, +103MB)
    const size_t offRS = (size_t)M_DIM * K_DIM;            // 4 MB
    const size_t offW  = offRS + (4u << 20);               // 8 MB
    const size_t need  = offW + (size_t)V_PAD * K_DIM;     // ~111 MB
    if (ws_size >= need) {
        char*  a8    = (char*)d_ws;
        float* rowsc = (float*)((char*)d_ws + offRS);
        char*  wt8   = (char*)d_ws + offW;
        prep<<<dim3(CVTW_BLOCKS + M_DIM), dim3(256), 0, stream>>>(hs, wq, a8, rowsc, wt8);
        lmhead_gemm_i8<<<dim3(16 * (V_PAD / BN)), dim3(256), 0, stream>>>(
            a8, rowsc, wt8, scale, bias, out);
    } else {
        lmhead_gemm_fb<<<dim3(M_DIM / 128, (V_DIM + 127) / 128), dim3(256), 0, stream>>>(
            hs, wq, scale, bias, out);
    }
}